// Round 1
// baseline (1495.841 us; speedup 1.0000x reference)
//
#include <hip/hip_runtime.h>
#include <math.h>

#define N_IMG 32
#define CIN   256
#define CMID  128
#define COUT  512
#define HH    56
#define HWP   (56*56)      // 3136
#define BN_EPS_F 1e-3f
#define ALPHA_F  10.0f
#define ARELU_S  25.5f     // (2^8 - 1) / alpha

// ---------------- workspace layout (in floats) ----------------
// wq1 : [0, 32768)                128*256
// wq2 : [32768, 180224)           128*128*9
// wq3 : [180224, 245760)          512*128
// bq1 : [245760, 245888)
// bq2 : [245888, 246016)
// bq3 : [246016, 246528)
// maxw: [246528, 246532)  (3 uints used)
// act1: [246784, 246784+12845056)
// act2: act1 + 12845056
#define OFF_WQ1 0
#define OFF_WQ2 32768
#define OFF_WQ3 180224
#define OFF_BQ1 245760
#define OFF_BQ2 245888
#define OFF_BQ3 246016
#define OFF_MAX 246528
#define OFF_A1  246784
#define ACT_ELEMS (N_IMG * CMID * HWP)   // 12,845,056

// ---------------- fold BN into weights + track |max| ----------------
__global__ __launch_bounds__(256) void fold_max_kernel(
    const float* __restrict__ w, const float* __restrict__ g,
    const float* __restrict__ v, float* __restrict__ wf,
    unsigned int* __restrict__ maxbits, int inner, int total)
{
    __shared__ float smax[256];
    float m = 0.f;
    for (int i = blockIdx.x * 256 + threadIdx.x; i < total; i += gridDim.x * 256) {
        int o = i / inner;
        float sc = g[o] / sqrtf(v[o] + BN_EPS_F);
        float val = w[i] * sc;
        wf[i] = val;
        m = fmaxf(m, fabsf(val));
    }
    smax[threadIdx.x] = m;
    __syncthreads();
    for (int s = 128; s > 0; s >>= 1) {
        if (threadIdx.x < s) smax[threadIdx.x] = fmaxf(smax[threadIdx.x], smax[threadIdx.x + s]);
        __syncthreads();
    }
    if (threadIdx.x == 0) atomicMax(maxbits, __float_as_uint(smax[0]));
}

// ---------------- symmetric quantize weights in place ----------------
__global__ __launch_bounds__(256) void quant_w_kernel(
    float* __restrict__ wf, const unsigned int* __restrict__ maxbits, int total)
{
    float mx = fmaxf(__uint_as_float(*maxbits), 1e-8f);
    float s = 127.0f / mx;
    int i = blockIdx.x * 256 + threadIdx.x;
    if (i < total) wf[i] = rintf(wf[i] * s) / s;
}

// ---------------- fold + quantize bias (one block per conv) ----------------
__global__ __launch_bounds__(512) void fold_bias_kernel(
    const float* __restrict__ b, const float* __restrict__ g,
    const float* __restrict__ be, const float* __restrict__ m,
    const float* __restrict__ v, float* __restrict__ bq, int n)
{
    __shared__ float red[512];
    int t = threadIdx.x;
    float val = 0.f;
    if (t < n) {
        float sc = g[t] / sqrtf(v[t] + BN_EPS_F);
        val = (b[t] - m[t]) * sc + be[t];
    }
    red[t] = (t < n) ? fabsf(val) : 0.f;
    __syncthreads();
    for (int s = 256; s > 0; s >>= 1) {
        if (t < s) red[t] = fmaxf(red[t], red[t + s]);
        __syncthreads();
    }
    float mx = fmaxf(red[0], 1e-8f);
    float s = 32767.0f / mx;
    if (t < n) bq[t] = rintf(val * s) / s;
}

// ---------------- 1x1 conv as tiled GEMM (+bias, optional qrelu) ----------------
// C[n, m, p] = sum_k W[m,k] * X[n,k,p] + B[m];  tile 64(m) x 64(p), BK=16
template<int M, int K, bool RELU>
__global__ __launch_bounds__(256) void conv1x1_kernel(
    const float* __restrict__ X, const float* __restrict__ Wq,
    const float* __restrict__ Bq, float* __restrict__ Y)
{
    const int n  = blockIdx.z;
    const int p0 = blockIdx.x * 64;
    const int m0 = blockIdx.y * 64;
    const float* Xn = X + (size_t)n * K * HWP;
    float* Yn = Y + (size_t)n * M * HWP;

    __shared__ float As[16][64 + 1];   // As[k][m]
    __shared__ float Bs[16][64 + 1];   // Bs[k][p]
    const int tid = threadIdx.x;
    const int tx = tid & 15;
    const int ty = tid >> 4;

    float acc[4][4] = {};

    // load index precompute
    const int ai = tid >> 2;          // 0..63  (m within tile)
    const int aj = (tid & 3) * 4;     // 0..12  (k within chunk)
    const int bj = tid >> 4;          // 0..15  (k within chunk)
    const int bi = (tid & 15) * 4;    // 0..60  (p within tile)

    for (int k0 = 0; k0 < K; k0 += 16) {
        float4 av = *(const float4*)(&Wq[(size_t)(m0 + ai) * K + k0 + aj]);
        float4 bv = *(const float4*)(&Xn[(size_t)(k0 + bj) * HWP + p0 + bi]);
        As[aj + 0][ai] = av.x; As[aj + 1][ai] = av.y;
        As[aj + 2][ai] = av.z; As[aj + 3][ai] = av.w;
        *(float4*)(&Bs[bj][bi]) = bv;
        __syncthreads();
#pragma unroll
        for (int kk = 0; kk < 16; kk++) {
            float a[4], b[4];
#pragma unroll
            for (int i = 0; i < 4; i++) a[i] = As[kk][ty * 4 + i];
#pragma unroll
            for (int i = 0; i < 4; i++) b[i] = Bs[kk][tx * 4 + i];
#pragma unroll
            for (int i = 0; i < 4; i++)
#pragma unroll
                for (int j = 0; j < 4; j++) acc[i][j] = fmaf(a[i], b[j], acc[i][j]);
        }
        __syncthreads();
    }

#pragma unroll
    for (int i = 0; i < 4; i++) {
        int m = m0 + ty * 4 + i;
        float bias = Bq[m];
        float4 o;
        float vv[4];
#pragma unroll
        for (int j = 0; j < 4; j++) {
            float val = acc[i][j] + bias;
            if (RELU) {
                val = fminf(fmaxf(val, 0.f), ALPHA_F);
                val = rintf(val * ARELU_S) / ARELU_S;
            }
            vv[j] = val;
        }
        o.x = vv[0]; o.y = vv[1]; o.z = vv[2]; o.w = vv[3];
        *(float4*)(&Yn[(size_t)m * HWP + p0 + tx * 4]) = o;
    }
}

// ---------------- 3x3 conv (pad 1) as implicit GEMM + qrelu ----------------
__global__ __launch_bounds__(256) void conv3x3_kernel(
    const float* __restrict__ X, const float* __restrict__ Wq,
    const float* __restrict__ Bq, float* __restrict__ Y)
{
    const int n  = blockIdx.z;
    const int p0 = blockIdx.x * 64;
    const int m0 = blockIdx.y * 64;
    const float* Xn = X + (size_t)n * CMID * HWP;
    float* Yn = Y + (size_t)n * CMID * HWP;

    __shared__ float As[16][64 + 1];
    __shared__ float Bs[16][64 + 1];
    const int tid = threadIdx.x;
    const int tx = tid & 15;
    const int ty = tid >> 4;

    float acc[4][4] = {};

    const int ai = tid >> 2;          // m within tile (0..63)
    const int aj = (tid & 3) * 4;     // k within chunk
    const int bj = tid >> 4;          // k within chunk (0..15)
    const int bi = (tid & 15) * 4;    // p within tile

    // this thread's 4 pixel coords
    int py[4], px[4];
#pragma unroll
    for (int t = 0; t < 4; t++) {
        int p = p0 + bi + t;
        py[t] = p / 56;
        px[t] = p - py[t] * 56;
    }

    for (int tap = 0; tap < 9; tap++) {
        const int dy = tap / 3 - 1;
        const int dx = tap % 3 - 1;
        int soff[4];
        bool sval[4];
#pragma unroll
        for (int t = 0; t < 4; t++) {
            int ys = py[t] + dy, xs = px[t] + dx;
            sval[t] = ((unsigned)ys < 56u) && ((unsigned)xs < 56u);
            soff[t] = ys * 56 + xs;
        }
        const size_t wbase = (size_t)(m0 + ai) * CMID * 9 + tap;
        for (int c0 = 0; c0 < CMID; c0 += 16) {
#pragma unroll
            for (int t = 0; t < 4; t++)
                As[aj + t][ai] = Wq[wbase + (size_t)(c0 + aj + t) * 9];
            const float* Xrow = Xn + (size_t)(c0 + bj) * HWP;
#pragma unroll
            for (int t = 0; t < 4; t++)
                Bs[bj][bi + t] = sval[t] ? Xrow[soff[t]] : 0.f;
            __syncthreads();
#pragma unroll
            for (int kk = 0; kk < 16; kk++) {
                float a[4], b[4];
#pragma unroll
                for (int i = 0; i < 4; i++) a[i] = As[kk][ty * 4 + i];
#pragma unroll
                for (int i = 0; i < 4; i++) b[i] = Bs[kk][tx * 4 + i];
#pragma unroll
                for (int i = 0; i < 4; i++)
#pragma unroll
                    for (int j = 0; j < 4; j++) acc[i][j] = fmaf(a[i], b[j], acc[i][j]);
            }
            __syncthreads();
        }
    }

#pragma unroll
    for (int i = 0; i < 4; i++) {
        int m = m0 + ty * 4 + i;
        float bias = Bq[m];
        float4 o;
        float vv[4];
#pragma unroll
        for (int j = 0; j < 4; j++) {
            float val = acc[i][j] + bias;
            val = fminf(fmaxf(val, 0.f), ALPHA_F);
            val = rintf(val * ARELU_S) / ARELU_S;
            vv[j] = val;
        }
        o.x = vv[0]; o.y = vv[1]; o.z = vv[2]; o.w = vv[3];
        *(float4*)(&Yn[(size_t)m * HWP + p0 + tx * 4]) = o;
    }
}

extern "C" void kernel_launch(void* const* d_in, const int* in_sizes, int n_in,
                              void* d_out, int out_size, void* d_ws, size_t ws_size,
                              hipStream_t stream) {
    const float* x   = (const float*)d_in[0];
    const float* w1  = (const float*)d_in[1];
    const float* b1  = (const float*)d_in[2];
    const float* g1  = (const float*)d_in[3];
    const float* be1 = (const float*)d_in[4];
    const float* m1  = (const float*)d_in[5];
    const float* v1  = (const float*)d_in[6];
    const float* w2  = (const float*)d_in[7];
    const float* b2  = (const float*)d_in[8];
    const float* g2  = (const float*)d_in[9];
    const float* be2 = (const float*)d_in[10];
    const float* m2  = (const float*)d_in[11];
    const float* v2  = (const float*)d_in[12];
    const float* w3  = (const float*)d_in[13];
    const float* b3  = (const float*)d_in[14];
    const float* g3  = (const float*)d_in[15];
    const float* be3 = (const float*)d_in[16];
    const float* m3  = (const float*)d_in[17];
    const float* v3  = (const float*)d_in[18];

    float* ws  = (float*)d_ws;
    float* wq1 = ws + OFF_WQ1;
    float* wq2 = ws + OFF_WQ2;
    float* wq3 = ws + OFF_WQ3;
    float* bq1 = ws + OFF_BQ1;
    float* bq2 = ws + OFF_BQ2;
    float* bq3 = ws + OFF_BQ3;
    unsigned int* maxw = (unsigned int*)(ws + OFF_MAX);
    float* act1 = ws + OFF_A1;
    float* act2 = act1 + ACT_ELEMS;
    float* out  = (float*)d_out;

    // zero the atomic-max slots (ws is poisoned to 0xAA)
    hipMemsetAsync(maxw, 0, 3 * sizeof(unsigned int), stream);

    // fold BN into weights + per-tensor |max|
    fold_max_kernel<<<128, 256, 0, stream>>>(w1, g1, v1, wq1, maxw + 0, CIN,      CMID * CIN);
    fold_max_kernel<<<256, 256, 0, stream>>>(w2, g2, v2, wq2, maxw + 1, CMID * 9, CMID * CMID * 9);
    fold_max_kernel<<<256, 256, 0, stream>>>(w3, g3, v3, wq3, maxw + 2, CMID,     COUT * CMID);

    // quantize weights (8-bit symmetric, per tensor)
    quant_w_kernel<<<(CMID * CIN) / 256,      256, 0, stream>>>(wq1, maxw + 0, CMID * CIN);
    quant_w_kernel<<<(CMID * CMID * 9) / 256, 256, 0, stream>>>(wq2, maxw + 1, CMID * CMID * 9);
    quant_w_kernel<<<(COUT * CMID) / 256,     256, 0, stream>>>(wq3, maxw + 2, COUT * CMID);

    // fold + quantize biases (16-bit symmetric)
    fold_bias_kernel<<<1, 512, 0, stream>>>(b1, g1, be1, m1, v1, bq1, CMID);
    fold_bias_kernel<<<1, 512, 0, stream>>>(b2, g2, be2, m2, v2, bq2, CMID);
    fold_bias_kernel<<<1, 512, 0, stream>>>(b3, g3, be3, m3, v3, bq3, COUT);

    // conv1 (1x1, 256->128) + qrelu
    conv1x1_kernel<CMID, CIN, true><<<dim3(49, 2, 32), 256, 0, stream>>>(x, wq1, bq1, act1);
    // conv2 (3x3 pad 1, 128->128) + qrelu
    conv3x3_kernel<<<dim3(49, 2, 32), 256, 0, stream>>>(act1, wq2, bq2, act2);
    // conv3 (1x1, 128->512) + bias (no relu)
    conv1x1_kernel<COUT, CMID, false><<<dim3(49, 8, 32), 256, 0, stream>>>(act2, wq3, bq3, out);
}

// Round 2
// 613.206 us; speedup vs baseline: 2.4394x; 2.4394x over previous
//
#include <hip/hip_runtime.h>
#include <math.h>

typedef int v4i  __attribute__((ext_vector_type(4)));
typedef int v16i __attribute__((ext_vector_type(16)));

#define N_IMG 32
#define CIN   256
#define CMID  128
#define COUT  512
#define HWP   3136
#define W58   58
#define PLANE_Q 3456            // 27 tiles of 128 (3364 valid padded positions + tail)
#define CBSTRIDE (PLANE_Q*16)   // 55296 bytes per 16-channel plane
#define IMGSTRIDE (8*CBSTRIDE)  // 442368 bytes per image (128 ch)
#define BSROW 248               // staged halo rows (246 used)
#define GUARD 16384
#define BN_EPS_F 1e-3f
#define ALPHA_F  10.0f
#define ARELU_S  25.5f

// ---------------- workspace layout (float units unless noted) ----------------
#define OFF_WQ1   0            // 32768 fp32 (conv1 weights, quantized fp32)
#define OFF_WF2   32768        // 147456 fp32 (folded w2, temp)
#define OFF_WF3   180224       // 65536 fp32 (folded w3, temp)
#define OFF_BQ1   245760
#define OFF_BQ2   245888
#define OFF_BQ3   246016
#define OFF_MAX   246528       // 3 uints
#define OFF_Q2    246536       // 128 ints
#define OFF_Q3    246664       // 512 ints
#define OFF_WQ2I  247296       // i8 [9][128][128] = 147456 B (36864 floats)
#define OFF_WQ3I  284160       // i8 [512][128]    = 65536 B  (16384 floats)
#define OFF_ACT1F 300544       // fp32 act1 [32][128][3136]
// byte offsets for i8 activation planes:
#define ACT1Q_GUARD_B 52582400u            // = (OFF_ACT1F + 12845056)*4
#define ACT1Q_B       (ACT1Q_GUARD_B + GUARD)
#define ACT2Q_B       (ACT1Q_B + (unsigned)(N_IMG*IMGSTRIDE) + GUARD)

__device__ __forceinline__ void async16(const char* g, char* l) {
    __builtin_amdgcn_global_load_lds((const __attribute__((address_space(1))) void*)g,
                                     (__attribute__((address_space(3))) void*)l, 16, 0, 0);
}

// ---------------- fold BN into weights + track |max| ----------------
__global__ __launch_bounds__(256) void fold_max_kernel(
    const float* __restrict__ w, const float* __restrict__ g,
    const float* __restrict__ v, float* __restrict__ wf,
    unsigned int* __restrict__ maxbits, int inner, int total)
{
    __shared__ float smax[256];
    float m = 0.f;
    for (int i = blockIdx.x * 256 + threadIdx.x; i < total; i += gridDim.x * 256) {
        int o = i / inner;
        float sc = g[o] / sqrtf(v[o] + BN_EPS_F);
        float val = w[i] * sc;
        wf[i] = val;
        m = fmaxf(m, fabsf(val));
    }
    smax[threadIdx.x] = m;
    __syncthreads();
    for (int s = 128; s > 0; s >>= 1) {
        if (threadIdx.x < s) smax[threadIdx.x] = fmaxf(smax[threadIdx.x], smax[threadIdx.x + s]);
        __syncthreads();
    }
    if (threadIdx.x == 0) atomicMax(maxbits, __float_as_uint(smax[0]));
}

// ---------------- quantize conv1 weights (stay fp32) ----------------
__global__ __launch_bounds__(256) void quant_w_kernel(
    float* __restrict__ wf, const unsigned int* __restrict__ maxbits, int total)
{
    float mx = fmaxf(__uint_as_float(*maxbits), 1e-8f);
    float s = 127.0f / mx;
    int i = blockIdx.x * 256 + threadIdx.x;
    if (i < total) wf[i] = rintf(wf[i] * s) / s;
}

// ---------------- quantize w2 to i8, layout [tap][m][c], plus Q2[m]=sum q ----------------
__global__ __launch_bounds__(256) void quant_w2_kernel(
    const float* __restrict__ wf2, const unsigned int* __restrict__ maxw,
    char* __restrict__ wq2i, int* __restrict__ Q2)
{
    __shared__ int red[256];
    int m = blockIdx.x;
    float s = 127.0f / fmaxf(__uint_as_float(maxw[1]), 1e-8f);
    int sum = 0;
    for (int idx = threadIdx.x; idx < CMID * 9; idx += 256) {
        int c = idx / 9, tap = idx - c * 9;
        int q = (int)rintf(wf2[(size_t)m * (CMID * 9) + idx] * s);
        wq2i[(size_t)tap * (CMID * CMID) + m * CMID + c] = (char)q;
        sum += q;
    }
    red[threadIdx.x] = sum;
    __syncthreads();
    for (int st = 128; st > 0; st >>= 1) {
        if (threadIdx.x < st) red[threadIdx.x] += red[threadIdx.x + st];
        __syncthreads();
    }
    if (threadIdx.x == 0) Q2[m] = red[0];
}

// ---------------- quantize w3 to i8, layout [m][c], plus Q3[m] ----------------
__global__ __launch_bounds__(128) void quant_w3_kernel(
    const float* __restrict__ wf3, const unsigned int* __restrict__ maxw,
    char* __restrict__ wq3i, int* __restrict__ Q3)
{
    __shared__ int red[128];
    int m = blockIdx.x, c = threadIdx.x;
    float s = 127.0f / fmaxf(__uint_as_float(maxw[2]), 1e-8f);
    int q = (int)rintf(wf3[(size_t)m * CMID + c] * s);
    wq3i[(size_t)m * CMID + c] = (char)q;
    red[c] = q;
    __syncthreads();
    for (int st = 64; st > 0; st >>= 1) {
        if (c < st) red[c] += red[c + st];
        __syncthreads();
    }
    if (c == 0) Q3[m] = red[0];
}

// ---------------- fold + quantize bias ----------------
__global__ __launch_bounds__(512) void fold_bias_kernel(
    const float* __restrict__ b, const float* __restrict__ g,
    const float* __restrict__ be, const float* __restrict__ m,
    const float* __restrict__ v, float* __restrict__ bq, int n)
{
    __shared__ float red[512];
    int t = threadIdx.x;
    float val = 0.f;
    if (t < n) {
        float sc = g[t] / sqrtf(v[t] + BN_EPS_F);
        val = (b[t] - m[t]) * sc + be[t];
    }
    red[t] = (t < n) ? fabsf(val) : 0.f;
    __syncthreads();
    for (int s = 256; s > 0; s >>= 1) {
        if (t < s) red[t] = fmaxf(red[t], red[t + s]);
        __syncthreads();
    }
    float mx = fmaxf(red[0], 1e-8f);
    float s = 32767.0f / mx;
    if (t < n) bq[t] = rintf(val * s) / s;
}

// ---------------- conv1: 1x1 fp32 tiled GEMM + qrelu (unchanged from R1) ----------------
template<int M, int K, bool RELU>
__global__ __launch_bounds__(256) void conv1x1_kernel(
    const float* __restrict__ X, const float* __restrict__ Wq,
    const float* __restrict__ Bq, float* __restrict__ Y)
{
    const int n  = blockIdx.z;
    const int p0 = blockIdx.x * 64;
    const int m0 = blockIdx.y * 64;
    const float* Xn = X + (size_t)n * K * HWP;
    float* Yn = Y + (size_t)n * M * HWP;

    __shared__ float As[16][64 + 1];
    __shared__ float Bs[16][64 + 1];
    const int tid = threadIdx.x;
    const int tx = tid & 15;
    const int ty = tid >> 4;
    float acc[4][4] = {};

    const int ai = tid >> 2;
    const int aj = (tid & 3) * 4;
    const int bj = tid >> 4;
    const int bi = (tid & 15) * 4;

    for (int k0 = 0; k0 < K; k0 += 16) {
        float4 av = *(const float4*)(&Wq[(size_t)(m0 + ai) * K + k0 + aj]);
        float4 bv = *(const float4*)(&Xn[(size_t)(k0 + bj) * HWP + p0 + bi]);
        As[aj + 0][ai] = av.x; As[aj + 1][ai] = av.y;
        As[aj + 2][ai] = av.z; As[aj + 3][ai] = av.w;
        *(float4*)(&Bs[bj][bi]) = bv;
        __syncthreads();
#pragma unroll
        for (int kk = 0; kk < 16; kk++) {
            float a[4], b[4];
#pragma unroll
            for (int i = 0; i < 4; i++) a[i] = As[kk][ty * 4 + i];
#pragma unroll
            for (int i = 0; i < 4; i++) b[i] = Bs[kk][tx * 4 + i];
#pragma unroll
            for (int i = 0; i < 4; i++)
#pragma unroll
                for (int j = 0; j < 4; j++) acc[i][j] = fmaf(a[i], b[j], acc[i][j]);
        }
        __syncthreads();
    }

#pragma unroll
    for (int i = 0; i < 4; i++) {
        int m = m0 + ty * 4 + i;
        float bias = Bq[m];
        float4 o; float vv[4];
#pragma unroll
        for (int j = 0; j < 4; j++) {
            float val = acc[i][j] + bias;
            if (RELU) {
                val = fminf(fmaxf(val, 0.f), ALPHA_F);
                val = rintf(val * ARELU_S) / ARELU_S;
            }
            vv[j] = val;
        }
        o.x = vv[0]; o.y = vv[1]; o.z = vv[2]; o.w = vv[3];
        *(float4*)(&Yn[(size_t)m * HWP + p0 + tx * 4]) = o;
    }
}

// ---------------- repack act1 fp32 [n][c][p] -> i8 (k-128) padded [n][cb][q][16] ----------------
__global__ __launch_bounds__(256) void repack_kernel(
    const float* __restrict__ act1f, char* __restrict__ actq)
{
    int n = blockIdx.y;
    int p = blockIdx.x * 256 + threadIdx.x;
    if (p >= HWP) return;
    int y = p / 56, x = p - y * 56;
    int q = (y + 1) * W58 + (x + 1);
    const float* srcp = act1f + (size_t)n * CMID * HWP + p;
    char* dst = actq + (size_t)n * IMGSTRIDE + q * 16;
#pragma unroll
    for (int cb = 0; cb < 8; cb++) {
        int w[4] = {0, 0, 0, 0};
#pragma unroll
        for (int j = 0; j < 16; j++) {
            float v = srcp[(size_t)(cb * 16 + j) * HWP];
            int k = (int)rintf(v * ARELU_S);        // exact recovery of quant level
            w[j >> 2] |= ((k - 128) & 255) << ((j & 3) * 8);
        }
        *(int4*)(dst + (size_t)cb * CBSTRIDE) = make_int4(w[0], w[1], w[2], w[3]);
    }
}

// ---------------- conv2: 3x3 pad1 i8 MFMA implicit GEMM + qrelu -> i8 ----------------
__global__ __launch_bounds__(256) void conv2_i8_kernel(
    const char* __restrict__ actq, const char* __restrict__ wq2i,
    const int* __restrict__ Q2, const float* __restrict__ bq2,
    const unsigned int* __restrict__ maxw, char* __restrict__ act2q)
{
    __shared__ char lds[48128];
    char* As2 = lds;            // [8 cb][128 m][16]
    char* Bs  = lds + 16384;    // [8 cb][BSROW q][16]
    const int tid = threadIdx.x;
    const int n  = blockIdx.z;
    const int q0 = blockIdx.x * 128;
    const int lane = tid & 63, wid = tid >> 6;
    const int lo = lane & 31, hi = lane >> 5;
    const int wm = wid >> 1, wn = wid & 1;

    // stage B halo: rows q0-59 .. q0+186, all 8 cb planes (guards cover under/overflow)
    const char* src = actq + (size_t)n * IMGSTRIDE + (long)(q0 - 59) * 16;
#pragma unroll
    for (int cb = 0; cb < 8; cb++) {
        if (tid < 246)
            async16(src + (size_t)cb * CBSTRIDE + tid * 16, Bs + cb * (BSROW * 16) + tid * 16);
    }

    // weight-staging addressing: thread -> (m = tid>>1, half = tid&1)
    const int sm = tid >> 1, shalf = tid & 1;
    const char* wsrc = wq2i + sm * CMID + shalf * 64;
    char* wdst = As2 + (shalf * 4) * 2048 + sm * 16;   // ((half*4+i)*128 + m)*16
    int4 pre[4];
#pragma unroll
    for (int i = 0; i < 4; i++) pre[i] = *(const int4*)(wsrc + i * 16);

    v16i acc[2][2] = {};

    for (int tap = 0; tap < 9; tap++) {
        __syncthreads();                      // prior tap's As reads done (and B DMA drained, 1st iter)
        int4 cur[4];
#pragma unroll
        for (int i = 0; i < 4; i++) cur[i] = pre[i];
        if (tap < 8) {
            const char* ns = wsrc + (size_t)(tap + 1) * (CMID * CMID);
#pragma unroll
            for (int i = 0; i < 4; i++) pre[i] = *(const int4*)(ns + i * 16);
        }
#pragma unroll
        for (int i = 0; i < 4; i++) *(int4*)(wdst + i * 2048) = cur[i];
        __syncthreads();                      // As for this tap visible

        const int tapoff = ((tap / 3) - 1) * W58 + (tap % 3) - 1;
#pragma unroll
        for (int ks = 0; ks < 4; ks++) {
            v4i a[2], b[2];
#pragma unroll
            for (int s = 0; s < 2; s++)
                a[s] = *(const v4i*)(As2 + ((ks * 2 + hi) * 128 + wm * 64 + s * 32 + lo) * 16);
#pragma unroll
            for (int t = 0; t < 2; t++) {
                int ql = 59 + tapoff + wn * 64 + t * 32 + lo;
                b[t] = *(const v4i*)(Bs + ((ks * 2 + hi) * BSROW + ql) * 16);
            }
#pragma unroll
            for (int s = 0; s < 2; s++)
#pragma unroll
                for (int t = 0; t < 2; t++)
                    acc[s][t] = __builtin_amdgcn_mfma_i32_32x32x32_i8(a[s], b[t], acc[s][t], 0, 0, 0);
        }
    }

    // epilogue: dequant + qrelu -> bytes, transpose via LDS, contiguous store
    float scale = fmaxf(__uint_as_float(maxw[1]), 1e-8f) / (127.0f * ARELU_S);
    __syncthreads();
    char* Cs = lds;                           // [128 q][148] (pad for bank spread)
#pragma unroll
    for (int s = 0; s < 2; s++)
#pragma unroll
        for (int t = 0; t < 2; t++) {
            int qloc = wn * 64 + t * 32 + lo;
#pragma unroll
            for (int reg = 0; reg < 16; reg++) {
                int m = wm * 64 + s * 32 + (reg & 3) + 8 * (reg >> 2) + 4 * hi;
                float val = fmaf((float)(acc[s][t][reg] + 128 * Q2[m]), scale, bq2[m]);
                val = fminf(fmaxf(val, 0.f), ALPHA_F);
                int k2 = (int)rintf(val * ARELU_S);
                Cs[qloc * 148 + m] = (char)(k2 - 128);
            }
        }
    __syncthreads();
    char* dst = act2q + (size_t)n * IMGSTRIDE + q0 * 16;
#pragma unroll
    for (int it = 0; it < 4; it++) {
        int idx = it * 256 + tid;             // 0..1023 -> (q, cb)
        int q = idx >> 3, cb = idx & 7;
        int4 w;
        w.x = *(const int*)(Cs + q * 148 + cb * 16 + 0);
        w.y = *(const int*)(Cs + q * 148 + cb * 16 + 4);
        w.z = *(const int*)(Cs + q * 148 + cb * 16 + 8);
        w.w = *(const int*)(Cs + q * 148 + cb * 16 + 12);
        *(int4*)(dst + (size_t)cb * CBSTRIDE + q * 16) = w;
    }
}

// ---------------- conv3: 1x1 i8 MFMA GEMM -> fp32 out (masked store) ----------------
__global__ __launch_bounds__(256) void conv3_i8_kernel(
    const char* __restrict__ act2q, const char* __restrict__ wq3i,
    const int* __restrict__ Q3, const float* __restrict__ bq3,
    const unsigned int* __restrict__ maxw, float* __restrict__ out)
{
    __shared__ char lds[32768];
    char* As2 = lds;            // [8 cb][128 m][16]
    char* Bs  = lds + 16384;    // [8 cb][128 q][16]
    const int tid = threadIdx.x;
    const int n  = blockIdx.z;
    const int q0 = blockIdx.x * 128;
    const int m0 = blockIdx.y * 128;
    const int lane = tid & 63, wid = tid >> 6;
    const int lo = lane & 31, hi = lane >> 5;
    const int wm = wid >> 1, wn = wid & 1;

    const char* bsrc = act2q + (size_t)n * IMGSTRIDE + q0 * 16;
#pragma unroll
    for (int i = 0; i < 4; i++) {
        int cb = i * 2 + (tid >> 7), row = tid & 127;
        async16(bsrc + (size_t)cb * CBSTRIDE + row * 16, Bs + cb * 2048 + row * 16);
    }

    const int sm = tid >> 1, shalf = tid & 1;
    const char* wsrc = wq3i + (size_t)(m0 + sm) * CMID + shalf * 64;
    char* wdst = As2 + (shalf * 4) * 2048 + sm * 16;
    int4 w[4];
#pragma unroll
    for (int i = 0; i < 4; i++) w[i] = *(const int4*)(wsrc + i * 16);
#pragma unroll
    for (int i = 0; i < 4; i++) *(int4*)(wdst + i * 2048) = w[i];
    __syncthreads();

    v16i acc[2][2] = {};
#pragma unroll
    for (int ks = 0; ks < 4; ks++) {
        v4i a[2], b[2];
#pragma unroll
        for (int s = 0; s < 2; s++)
            a[s] = *(const v4i*)(As2 + ((ks * 2 + hi) * 128 + wm * 64 + s * 32 + lo) * 16);
#pragma unroll
        for (int t = 0; t < 2; t++)
            b[t] = *(const v4i*)(Bs + ((ks * 2 + hi) * 128 + wn * 64 + t * 32 + lo) * 16);
#pragma unroll
        for (int s = 0; s < 2; s++)
#pragma unroll
            for (int t = 0; t < 2; t++)
                acc[s][t] = __builtin_amdgcn_mfma_i32_32x32x32_i8(a[s], b[t], acc[s][t], 0, 0, 0);
    }

    float scale = fmaxf(__uint_as_float(maxw[2]), 1e-8f) / (127.0f * ARELU_S);
#pragma unroll
    for (int s = 0; s < 2; s++)
#pragma unroll
        for (int t = 0; t < 2; t++) {
            int q = q0 + wn * 64 + t * 32 + lo;
            int y = q / W58, x = q - y * W58;
            if ((unsigned)(y - 1) < 56u && (unsigned)(x - 1) < 56u) {
                int p = (y - 1) * 56 + (x - 1);
                float* op = out + (size_t)n * COUT * HWP + p;
#pragma unroll
                for (int reg = 0; reg < 16; reg++) {
                    int m = m0 + wm * 64 + s * 32 + (reg & 3) + 8 * (reg >> 2) + 4 * hi;
                    op[(size_t)m * HWP] = fmaf((float)(acc[s][t][reg] + 128 * Q3[m]), scale, bq3[m]);
                }
            }
        }
}

extern "C" void kernel_launch(void* const* d_in, const int* in_sizes, int n_in,
                              void* d_out, int out_size, void* d_ws, size_t ws_size,
                              hipStream_t stream) {
    const float* x   = (const float*)d_in[0];
    const float* w1  = (const float*)d_in[1];
    const float* b1  = (const float*)d_in[2];
    const float* g1  = (const float*)d_in[3];
    const float* be1 = (const float*)d_in[4];
    const float* m1  = (const float*)d_in[5];
    const float* v1  = (const float*)d_in[6];
    const float* w2  = (const float*)d_in[7];
    const float* b2  = (const float*)d_in[8];
    const float* g2  = (const float*)d_in[9];
    const float* be2 = (const float*)d_in[10];
    const float* m2  = (const float*)d_in[11];
    const float* v2  = (const float*)d_in[12];
    const float* w3  = (const float*)d_in[13];
    const float* b3  = (const float*)d_in[14];
    const float* g3  = (const float*)d_in[15];
    const float* be3 = (const float*)d_in[16];
    const float* m3  = (const float*)d_in[17];
    const float* v3  = (const float*)d_in[18];

    float* ws  = (float*)d_ws;
    unsigned char* wsb = (unsigned char*)d_ws;
    float* wq1 = ws + OFF_WQ1;
    float* wf2 = ws + OFF_WF2;
    float* wf3 = ws + OFF_WF3;
    float* bq1 = ws + OFF_BQ1;
    float* bq2 = ws + OFF_BQ2;
    float* bq3 = ws + OFF_BQ3;
    unsigned int* maxw = (unsigned int*)(ws + OFF_MAX);
    int* Q2 = (int*)(ws + OFF_Q2);
    int* Q3 = (int*)(ws + OFF_Q3);
    char* wq2i = (char*)(ws + OFF_WQ2I);
    char* wq3i = (char*)(ws + OFF_WQ3I);
    float* act1f = ws + OFF_ACT1F;
    char* act1q = (char*)(wsb + ACT1Q_B);
    char* act2q = (char*)(wsb + ACT2Q_B);
    float* out  = (float*)d_out;

    hipMemsetAsync(maxw, 0, 12, stream);
    // act1 padded planes (+guards) to -128 == pad value (k=0)
    hipMemsetAsync(wsb + ACT1Q_GUARD_B, 0x80, (size_t)GUARD + (size_t)N_IMG * IMGSTRIDE + GUARD, stream);

    fold_max_kernel<<<128, 256, 0, stream>>>(w1, g1, v1, wq1, maxw + 0, CIN,      CMID * CIN);
    fold_max_kernel<<<256, 256, 0, stream>>>(w2, g2, v2, wf2, maxw + 1, CMID * 9, CMID * CMID * 9);
    fold_max_kernel<<<256, 256, 0, stream>>>(w3, g3, v3, wf3, maxw + 2, CMID,     COUT * CMID);

    quant_w_kernel<<<(CMID * CIN) / 256, 256, 0, stream>>>(wq1, maxw + 0, CMID * CIN);
    quant_w2_kernel<<<CMID, 256, 0, stream>>>(wf2, maxw, wq2i, Q2);
    quant_w3_kernel<<<COUT, 128, 0, stream>>>(wf3, maxw, wq3i, Q3);

    fold_bias_kernel<<<1, 512, 0, stream>>>(b1, g1, be1, m1, v1, bq1, CMID);
    fold_bias_kernel<<<1, 512, 0, stream>>>(b2, g2, be2, m2, v2, bq2, CMID);
    fold_bias_kernel<<<1, 512, 0, stream>>>(b3, g3, be3, m3, v3, bq3, COUT);

    // conv1 (fp32) -> act1f, then repack to padded i8
    conv1x1_kernel<CMID, CIN, true><<<dim3(49, 2, 32), 256, 0, stream>>>(x, wq1, bq1, act1f);
    repack_kernel<<<dim3(13, 32), 256, 0, stream>>>(act1f, act1q);

    // conv2 (3x3 i8 MFMA) -> act2q
    conv2_i8_kernel<<<dim3(27, 1, 32), 256, 0, stream>>>(act1q, wq2i, Q2, bq2, maxw, act2q);
    // conv3 (1x1 i8 MFMA) -> out
    conv3_i8_kernel<<<dim3(27, 4, 32), 256, 0, stream>>>(act2q, wq3i, Q3, bq3, maxw, out);
}